// Round 5
// baseline (160.488 us; speedup 1.0000x reference)
//
#include <hip/hip_runtime.h>

#define Nn 2048
#define FIN 512
#define FO 64
#define SHIFT 20.0f
#define NJT 32
#define PS 68                 // p_s row stride (floats): 272B -> 16B-aligned float4 rows
#define ZTOT (Nn * FO + Nn)   // osum + lsum floats (fallback path only)

// ---------------- K1: h = x @ W  (proven) + optional zeroing (fallback path) ----------------
__global__ __launch_bounds__(256) void gat_xw(const float* __restrict__ x,
                                              const float* __restrict__ W,
                                              float* __restrict__ h,
                                              float* __restrict__ z) {
    const int gt = blockIdx.x * 256 + threadIdx.x;
    if (z != nullptr && gt < ZTOT) z[gt] = 0.f;

    __shared__ float part[2][2][FO];
    const int wave = threadIdx.x >> 6;
    const int lane = threadIdx.x & 63;
    const int rs = wave >> 1;
    const int kh = wave & 1;
    int row = blockIdx.x * 2 + rs;
    row = __builtin_amdgcn_readfirstlane(row);
    const float* xr = x + (size_t)row * FIN + kh * (FIN / 2);
    const float* Wp = W + (size_t)kh * (FIN / 2) * FO;
    float acc = 0.f;
#pragma unroll 2
    for (int k = 0; k < FIN / 2; k += 8) {
        float4 xa = *(const float4*)(xr + k);
        float4 xb = *(const float4*)(xr + k + 4);
        acc = fmaf(xa.x, Wp[(k + 0) * FO + lane], acc);
        acc = fmaf(xa.y, Wp[(k + 1) * FO + lane], acc);
        acc = fmaf(xa.z, Wp[(k + 2) * FO + lane], acc);
        acc = fmaf(xa.w, Wp[(k + 3) * FO + lane], acc);
        acc = fmaf(xb.x, Wp[(k + 4) * FO + lane], acc);
        acc = fmaf(xb.y, Wp[(k + 5) * FO + lane], acc);
        acc = fmaf(xb.z, Wp[(k + 6) * FO + lane], acc);
        acc = fmaf(xb.w, Wp[(k + 7) * FO + lane], acc);
    }
    part[rs][kh][lane] = acc;
    __syncthreads();
    if (threadIdx.x < 128) {
        const int r2 = threadIdx.x >> 6;
        const int l2 = threadIdx.x & 63;
        h[((size_t)blockIdx.x * 2 + r2) * FO + l2] = part[r2][0][l2] + part[r2][1][l2];
    }
}

// ---------------- K2: lane-per-row attn, operands streamed from L1/L2, LDS only for p ----------------
// Block = 256 thr = 4 waves, tile 64i x 64j. Wave w: i in [ib+16w, ib+16w+16).
// Lane = (il = lane&15 -> i row, g = lane>>4 -> j group of 16).
// e-phase: hi/hj float4 straight from global (h = 512KB, L2-resident; 16 lanes share each
//   hj address -> broadcast-coalesced). p written to per-wave LDS tile (wave-private: NO barriers).
// PV: f-range split by g (16 accum regs/lane); p from LDS, hj from global.
// DS instrs/lane ~20 (was ~260); LDS bytes/block ~20KB (was ~1MB). VALU-bound by design.
template <bool ATOMIC>
__global__ __launch_bounds__(256, 4) void gat_attn5(const float* __restrict__ h,
                                                    const int* __restrict__ adj,
                                                    const float* __restrict__ a,
                                                    float* __restrict__ po,
                                                    float* __restrict__ pl) {
    __shared__ __align__(16) float p_s[4][16 * PS];   // per-wave p tile [il][j]

    const int tid = threadIdx.x;
    const int w = tid >> 6;
    const int lane = tid & 63;
    const int il = lane & 15;
    const int g = lane >> 4;
    const int it = blockIdx.x >> 5;          // 0..31
    const int jt = blockIdx.x & (NJT - 1);   // 0..31
    const int ib = it * 64;
    const int jb = jt * 64;
    const int i = ib + w * 16 + il;          // this lane's row
    const int jB = jb + g * 16;              // this lane's 16-j group base

    const float* hrow = h + (size_t)i * FO;

    // ---- e-phase: e[q][k] = sum_f a_f * |h[i][f] - h[jB+4q+k][f]| ----
    float e[4][4];
#pragma unroll
    for (int q = 0; q < 4; q++)
#pragma unroll
        for (int k = 0; k < 4; k++) e[q][k] = 0.f;

#pragma unroll 2
    for (int f4 = 0; f4 < 16; f4++) {
        const float4 av = *(const float4*)(a + f4 * 4);       // wave-uniform
        const float4 hi = *(const float4*)(hrow + f4 * 4);    // per-lane row, L1/L2-hot
#pragma unroll
        for (int q = 0; q < 4; q++) {
#pragma unroll
            for (int k = 0; k < 4; k++) {
                const float4 hj = *(const float4*)(h + (size_t)(jB + q * 4 + k) * FO + f4 * 4);
                e[q][k] = fmaf(fabsf(hi.x - hj.x), av.x, e[q][k]);
                e[q][k] = fmaf(fabsf(hi.y - hj.y), av.y, e[q][k]);
                e[q][k] = fmaf(fabsf(hi.z - hj.z), av.z, e[q][k]);
                e[q][k] = fmaf(fabsf(hi.w - hj.w), av.w, e[q][k]);
            }
        }
    }

    // ---- p = adj ? exp(relu(e) - SHIFT) : 0 ; stash into wave-private LDS tile ----
    float ls = 0.f;
#pragma unroll
    for (int q = 0; q < 4; q++) {
        const int4 am = *(const int4*)(adj + (size_t)i * Nn + jB + q * 4);
        float4 pq;
        pq.x = (am.x > 0) ? __expf(fmaxf(e[q][0], 0.f) - SHIFT) : 0.f;
        pq.y = (am.y > 0) ? __expf(fmaxf(e[q][1], 0.f) - SHIFT) : 0.f;
        pq.z = (am.z > 0) ? __expf(fmaxf(e[q][2], 0.f) - SHIFT) : 0.f;
        pq.w = (am.w > 0) ? __expf(fmaxf(e[q][3], 0.f) - SHIFT) : 0.f;
        ls += pq.x + pq.y + pq.z + pq.w;
        *(float4*)&p_s[w][il * PS + g * 16 + q * 4] = pq;     // same-wave order via lgkmcnt
    }

    // ---- PV: lane accumulates out[i][g*16 .. g*16+15] over all 64 j ----
    const int fo = g * 16;
    float4 o0 = make_float4(0.f, 0.f, 0.f, 0.f);
    float4 o1 = o0, o2 = o0, o3 = o0;
#pragma unroll 2
    for (int j4 = 0; j4 < 16; j4++) {
        const float4 p4 = *(const float4*)&p_s[w][il * PS + j4 * 4];
#pragma unroll
        for (int k = 0; k < 4; k++) {
            const float pk = (k == 0) ? p4.x : (k == 1) ? p4.y : (k == 2) ? p4.z : p4.w;
            const float* hj = h + (size_t)(jb + j4 * 4 + k) * FO + fo;
            const float4 h0 = *(const float4*)(hj);
            const float4 h1 = *(const float4*)(hj + 4);
            const float4 h2 = *(const float4*)(hj + 8);
            const float4 h3 = *(const float4*)(hj + 12);
            o0.x = fmaf(pk, h0.x, o0.x); o0.y = fmaf(pk, h0.y, o0.y);
            o0.z = fmaf(pk, h0.z, o0.z); o0.w = fmaf(pk, h0.w, o0.w);
            o1.x = fmaf(pk, h1.x, o1.x); o1.y = fmaf(pk, h1.y, o1.y);
            o1.z = fmaf(pk, h1.z, o1.z); o1.w = fmaf(pk, h1.w, o1.w);
            o2.x = fmaf(pk, h2.x, o2.x); o2.y = fmaf(pk, h2.y, o2.y);
            o2.z = fmaf(pk, h2.z, o2.z); o2.w = fmaf(pk, h2.w, o2.w);
            o3.x = fmaf(pk, h3.x, o3.x); o3.y = fmaf(pk, h3.y, o3.y);
            o3.z = fmaf(pk, h3.z, o3.z); o3.w = fmaf(pk, h3.w, o3.w);
        }
    }

    // ---- epilogue: ls summed across g (xor 16,32); po/pl partial stores ----
    float lv = ls;
    lv += __shfl_xor(lv, 16, 64);
    lv += __shfl_xor(lv, 32, 64);

    if constexpr (!ATOMIC) {
        if (lane < 16) pl[(size_t)jt * Nn + i] = lv;
        float* dst = po + ((size_t)jt * Nn + i) * FO + fo;
        *(float4*)(dst)      = o0;
        *(float4*)(dst + 4)  = o1;
        *(float4*)(dst + 8)  = o2;
        *(float4*)(dst + 12) = o3;
    } else {
        if (lane < 16) atomicAdd(&pl[i], lv);
        float* dst = po + (size_t)i * FO + fo;
        atomicAdd(dst + 0,  o0.x); atomicAdd(dst + 1,  o0.y);
        atomicAdd(dst + 2,  o0.z); atomicAdd(dst + 3,  o0.w);
        atomicAdd(dst + 4,  o1.x); atomicAdd(dst + 5,  o1.y);
        atomicAdd(dst + 6,  o1.z); atomicAdd(dst + 7,  o1.w);
        atomicAdd(dst + 8,  o2.x); atomicAdd(dst + 9,  o2.y);
        atomicAdd(dst + 10, o2.z); atomicAdd(dst + 11, o2.w);
        atomicAdd(dst + 12, o3.x); atomicAdd(dst + 13, o3.y);
        atomicAdd(dst + 14, o3.z); atomicAdd(dst + 15, o3.w);
    }
}

// ---------------- K3: out = relu(sum_jt po / sum_jt pl) ----------------
__global__ __launch_bounds__(256) void gat_reduce(const float* __restrict__ po,
                                                  const float* __restrict__ pl,
                                                  float* __restrict__ out) {
    const int t = blockIdx.x * 256 + threadIdx.x;   // grid 512 -> 131072 = Nn*FO
    const int i = t >> 6;
    float s = 0.f;
#pragma unroll
    for (int p = 0; p < NJT; p++) s += po[(size_t)p * (Nn * FO) + t];
    float l = 0.f;
#pragma unroll
    for (int p = 0; p < NJT; p++) l += pl[p * Nn + i];   // wave-uniform addr -> broadcast
    out[t] = fmaxf(s / l, 0.f);
}

// ---------------- fallback K3: out = relu(osum / lsum) ----------------
__global__ __launch_bounds__(256) void gat_fin(const float* __restrict__ osum,
                                               const float* __restrict__ lsum,
                                               float* __restrict__ out) {
    const int t = blockIdx.x * 256 + threadIdx.x;
    out[t] = fmaxf(osum[t] / lsum[t >> 6], 0.f);
}

extern "C" void kernel_launch(void* const* d_in, const int* in_sizes, int n_in,
                              void* d_out, int out_size, void* d_ws, size_t ws_size,
                              hipStream_t stream) {
    const float* x   = (const float*)d_in[0];
    const int*   adj = (const int*)d_in[1];
    const float* W   = (const float*)d_in[2];
    const float* a   = (const float*)d_in[3];
    float* out = (float*)d_out;

    float* h = (float*)d_ws;                                   // Nn*FO floats
    const size_t need = ((size_t)Nn * FO + (size_t)NJT * Nn * FO + (size_t)NJT * Nn) * 4;

    if (ws_size >= need) {
        // no-atomic path: private partials + reduction
        float* po = h + (size_t)Nn * FO;                       // NJT*Nn*FO floats
        float* pl = po + (size_t)NJT * Nn * FO;                // NJT*Nn floats
        gat_xw<<<dim3(1024), dim3(256), 0, stream>>>(x, W, h, nullptr);
        gat_attn5<false><<<dim3(32 * NJT), dim3(256), 0, stream>>>(h, adj, a, po, pl);
        gat_reduce<<<dim3(512), dim3(256), 0, stream>>>(po, pl, out);
    } else {
        // fallback: atomic accumulation (1.06 MB workspace)
        float* osum = h + (size_t)Nn * FO;
        float* lsum = osum + (size_t)Nn * FO;
        gat_xw<<<dim3(1024), dim3(256), 0, stream>>>(x, W, h, osum);   // zeros osum+lsum
        gat_attn5<true><<<dim3(32 * NJT), dim3(256), 0, stream>>>(h, adj, a, osum, lsum);
        gat_fin<<<dim3(512), dim3(256), 0, stream>>>(osum, lsum, out);
    }
}

// Round 6
// 133.660 us; speedup vs baseline: 1.2007x; 1.2007x over previous
//
#include <hip/hip_runtime.h>

#define Nn 2048
#define FIN 512
#define FO 64
#define SHIFT 20.0f
#define NJT 32
#define HS 68                 // hj_s row stride: 272B rows -> 16B-aligned float4 blocks
#define PTS 68                // pT row stride: 272B -> 16B-aligned float4 rows
#define ZTOT (Nn * FO + Nn)   // osum + lsum floats (fallback path only)

// f4-block XOR swizzle for hj_s (round-4-proven, read/write consistent).
#define HX(r, f) ((r) * HS + ((((f) >> 2) ^ (((r) >> 2) & 15)) << 2))

// ---------------- K1: h = x @ W  (proven) + optional zeroing (fallback path) ----------------
__global__ __launch_bounds__(256) void gat_xw(const float* __restrict__ x,
                                              const float* __restrict__ W,
                                              float* __restrict__ h,
                                              float* __restrict__ z) {
    const int gt = blockIdx.x * 256 + threadIdx.x;
    if (z != nullptr && gt < ZTOT) z[gt] = 0.f;

    __shared__ float part[2][2][FO];
    const int wave = threadIdx.x >> 6;
    const int lane = threadIdx.x & 63;
    const int rs = wave >> 1;
    const int kh = wave & 1;
    int row = blockIdx.x * 2 + rs;
    row = __builtin_amdgcn_readfirstlane(row);
    const float* xr = x + (size_t)row * FIN + kh * (FIN / 2);
    const float* Wp = W + (size_t)kh * (FIN / 2) * FO;
    float acc = 0.f;
#pragma unroll 2
    for (int k = 0; k < FIN / 2; k += 8) {
        float4 xa = *(const float4*)(xr + k);
        float4 xb = *(const float4*)(xr + k + 4);
        acc = fmaf(xa.x, Wp[(k + 0) * FO + lane], acc);
        acc = fmaf(xa.y, Wp[(k + 1) * FO + lane], acc);
        acc = fmaf(xa.z, Wp[(k + 2) * FO + lane], acc);
        acc = fmaf(xa.w, Wp[(k + 3) * FO + lane], acc);
        acc = fmaf(xb.x, Wp[(k + 4) * FO + lane], acc);
        acc = fmaf(xb.y, Wp[(k + 5) * FO + lane], acc);
        acc = fmaf(xb.z, Wp[(k + 6) * FO + lane], acc);
        acc = fmaf(xb.w, Wp[(k + 7) * FO + lane], acc);
    }
    part[rs][kh][lane] = acc;
    __syncthreads();
    if (threadIdx.x < 128) {
        const int r2 = threadIdx.x >> 6;
        const int l2 = threadIdx.x & 63;
        h[((size_t)blockIdx.x * 2 + r2) * FO + l2] = part[r2][0][l2] + part[r2][1][l2];
    }
}

// ---------------- K2: split-pipe attn -- hj via LDS, hi/PV-hj via L1/L2, pT wave-private ----------------
// Block = 256 thr = 4 waves, tile 64i x 64j (NJT=32 -> 1024 blocks, 4/CU, LDS 34.8KB).
// Lane maps identical to round-4 (proven): e-phase lane (li,lj) owns 4i x 4j;
// PV lane owns 4i x 4f (f = 4*lj). Changes vs round-4:
//   - hi read from global (16-lane broadcast/addr, 16KB i-tile L1-hot) -> no hi staging,
//     no union, only ONE barrier in the whole kernel.
//   - PV hj read from global (one coalesced 256B row per wave-instr, L1-hot).
//   - pT stays LDS but is wave-private: same-wave DS FIFO ordering, no barrier
//     (round-5 precedent passed the replay tripwires with this pattern).
// Per-lane: DS ~136 instrs / 2.2KB (was ~280 / 4.3KB); VMEM ~157 instrs (round-5's
// failure mode was 530). LDS and TA pipes now run concurrently.
template <bool ATOMIC>
__global__ __launch_bounds__(256, 4) void gat_attn6(const float* __restrict__ h,
                                                    const int* __restrict__ adj,
                                                    const float* __restrict__ a,
                                                    float* __restrict__ po,
                                                    float* __restrict__ pl) {
    __shared__ __align__(16) float hj_s[64 * HS];
    __shared__ __align__(16) float pT_s[64 * PTS];

    const int tid = threadIdx.x;
    const int w = tid >> 6;
    const int lane = tid & 63;
    const int li = lane & 3;
    const int lj = lane >> 2;
    const int it = blockIdx.x >> 5;          // 0..31
    const int jt = blockIdx.x & (NJT - 1);   // 0..31
    const int ib = it * 64;
    const int jb = jt * 64;
    const int iw = w * 16;

    // stage hj tile (64 x 64) -- pure float4, swizzled dest (round-4-proven)
    for (int g4 = tid; g4 < 1024; g4 += 256) {
        const int row = g4 >> 4;
        const int f0 = (g4 & 15) * 4;
        float4 u = *(const float4*)(h + (size_t)jb * FO + (size_t)g4 * 4);
        *(float4*)&hj_s[HX(row, f0)] = u;
    }
    __syncthreads();   // the only block-wide barrier

    // ---- e-phase: e[di][dj] = sum_f a_f * |hi - hj|, hi/a from global, hj from LDS ----
    float e[4][4];
#pragma unroll
    for (int di = 0; di < 4; di++)
#pragma unroll
        for (int dj = 0; dj < 4; dj++) e[di][dj] = 0.f;

    const float* hib = h + (size_t)(ib + iw + 4 * li) * FO;   // this lane's 4 i-rows

#pragma unroll 4
    for (int f4 = 0; f4 < 16; f4++) {
        const float4 av = *(const float4*)(a + f4 * 4);       // wave-uniform, L1-hot
        float4 hi4[4], hj4[4];
#pragma unroll
        for (int d = 0; d < 4; d++) {
            hi4[d] = *(const float4*)(hib + (size_t)d * FO + f4 * 4);   // 16-lane broadcast
            hj4[d] = *(const float4*)&hj_s[HX(4 * lj + d, f4 * 4)];
        }
#pragma unroll
        for (int di = 0; di < 4; di++)
#pragma unroll
            for (int dj = 0; dj < 4; dj++) {
                e[di][dj] = fmaf(fabsf(hi4[di].x - hj4[dj].x), av.x, e[di][dj]);
                e[di][dj] = fmaf(fabsf(hi4[di].y - hj4[dj].y), av.y, e[di][dj]);
                e[di][dj] = fmaf(fabsf(hi4[di].z - hj4[dj].z), av.z, e[di][dj]);
                e[di][dj] = fmaf(fabsf(hi4[di].w - hj4[dj].w), av.w, e[di][dj]);
            }
    }

    // ---- p = adj ? exp(relu(e) - SHIFT) : 0  (adj loaded late to cut e-phase pressure) ----
    float ls[4];
#pragma unroll
    for (int di = 0; di < 4; di++) ls[di] = 0.f;
#pragma unroll
    for (int di = 0; di < 4; di++) {
        const int4 am = *(const int4*)(adj + (size_t)(ib + iw + 4 * li + di) * Nn + (jb + 4 * lj));
        const int* ap = (const int*)&am;
#pragma unroll
        for (int dj = 0; dj < 4; dj++) {
            const float p = (ap[dj] > 0) ? __expf(fmaxf(e[di][dj], 0.f) - SHIFT) : 0.f;
            e[di][dj] = p;
            ls[di] += p;
        }
    }

    // transpose p through pT (wave-private column slice [iw, iw+16); same-wave DS FIFO,
    // no barrier needed -- writes and reads are within this wave's own column slice)
#pragma unroll
    for (int dj = 0; dj < 4; dj++) {
        *(float4*)&pT_s[(4 * lj + dj) * PTS + iw + 4 * li] =
            make_float4(e[0][dj], e[1][dj], e[2][dj], e[3][dj]);
    }

    // ---- PV: lane -> (4i x 4f): i = iw+4*li+di, f = 4*lj+v ; pj from LDS, hv from global ----
    float pv[4][4];
#pragma unroll
    for (int u = 0; u < 4; u++)
#pragma unroll
        for (int v2 = 0; v2 < 4; v2++) pv[u][v2] = 0.f;

#pragma unroll 4
    for (int j = 0; j < 64; j++) {
        const float4 pj = *(const float4*)&pT_s[j * PTS + iw + 4 * li];
        const float4 hv = *(const float4*)(h + (size_t)(jb + j) * FO + 4 * lj);  // coalesced row, L1-hot
        pv[0][0] = fmaf(pj.x, hv.x, pv[0][0]);
        pv[0][1] = fmaf(pj.x, hv.y, pv[0][1]);
        pv[0][2] = fmaf(pj.x, hv.z, pv[0][2]);
        pv[0][3] = fmaf(pj.x, hv.w, pv[0][3]);
        pv[1][0] = fmaf(pj.y, hv.x, pv[1][0]);
        pv[1][1] = fmaf(pj.y, hv.y, pv[1][1]);
        pv[1][2] = fmaf(pj.y, hv.z, pv[1][2]);
        pv[1][3] = fmaf(pj.y, hv.w, pv[1][3]);
        pv[2][0] = fmaf(pj.z, hv.x, pv[2][0]);
        pv[2][1] = fmaf(pj.z, hv.y, pv[2][1]);
        pv[2][2] = fmaf(pj.z, hv.z, pv[2][2]);
        pv[2][3] = fmaf(pj.z, hv.w, pv[2][3]);
        pv[3][0] = fmaf(pj.w, hv.x, pv[3][0]);
        pv[3][1] = fmaf(pj.w, hv.y, pv[3][1]);
        pv[3][2] = fmaf(pj.w, hv.z, pv[3][2]);
        pv[3][3] = fmaf(pj.w, hv.w, pv[3][3]);
    }

    // ---- epilogue: reduce l over lj lanes ----
#pragma unroll
    for (int di = 0; di < 4; di++) {
        float v = ls[di];
        v += __shfl_xor(v, 4, 64);
        v += __shfl_xor(v, 8, 64);
        v += __shfl_xor(v, 16, 64);
        v += __shfl_xor(v, 32, 64);
        ls[di] = v;
    }

    if constexpr (!ATOMIC) {
        if (lj == 0) {
#pragma unroll
            for (int di = 0; di < 4; di++)
                pl[(size_t)jt * Nn + (ib + iw + 4 * li + di)] = ls[di];
        }
#pragma unroll
        for (int di = 0; di < 4; di++)
            *(float4*)&po[((size_t)jt * Nn + (ib + iw + 4 * li + di)) * FO + 4 * lj] =
                make_float4(pv[di][0], pv[di][1], pv[di][2], pv[di][3]);
    } else {
        if (lj == 0) {
#pragma unroll
            for (int di = 0; di < 4; di++)
                atomicAdd(&pl[ib + iw + 4 * li + di], ls[di]);
        }
#pragma unroll
        for (int di = 0; di < 4; di++) {
#pragma unroll
            for (int v2 = 0; v2 < 4; v2++)
                atomicAdd(&po[(size_t)(ib + iw + 4 * li + di) * FO + 4 * lj + v2], pv[di][v2]);
        }
    }
}

// ---------------- K3: out = relu(sum_jt po / sum_jt pl) ----------------
__global__ __launch_bounds__(256) void gat_reduce(const float* __restrict__ po,
                                                  const float* __restrict__ pl,
                                                  float* __restrict__ out) {
    const int t = blockIdx.x * 256 + threadIdx.x;   // grid 512 -> 131072 = Nn*FO
    const int i = t >> 6;
    float s = 0.f;
#pragma unroll
    for (int p = 0; p < NJT; p++) s += po[(size_t)p * (Nn * FO) + t];
    float l = 0.f;
#pragma unroll
    for (int p = 0; p < NJT; p++) l += pl[p * Nn + i];   // wave-uniform addr -> broadcast
    out[t] = fmaxf(s / l, 0.f);
}

// ---------------- fallback K3: out = relu(osum / lsum) ----------------
__global__ __launch_bounds__(256) void gat_fin(const float* __restrict__ osum,
                                               const float* __restrict__ lsum,
                                               float* __restrict__ out) {
    const int t = blockIdx.x * 256 + threadIdx.x;
    out[t] = fmaxf(osum[t] / lsum[t >> 6], 0.f);
}

extern "C" void kernel_launch(void* const* d_in, const int* in_sizes, int n_in,
                              void* d_out, int out_size, void* d_ws, size_t ws_size,
                              hipStream_t stream) {
    const float* x   = (const float*)d_in[0];
    const int*   adj = (const int*)d_in[1];
    const float* W   = (const float*)d_in[2];
    const float* a   = (const float*)d_in[3];
    float* out = (float*)d_out;

    float* h = (float*)d_ws;                                   // Nn*FO floats
    const size_t need = ((size_t)Nn * FO + (size_t)NJT * Nn * FO + (size_t)NJT * Nn) * 4;

    if (ws_size >= need) {
        // no-atomic path: private partials + reduction
        float* po = h + (size_t)Nn * FO;                       // NJT*Nn*FO floats
        float* pl = po + (size_t)NJT * Nn * FO;                // NJT*Nn floats
        gat_xw<<<dim3(1024), dim3(256), 0, stream>>>(x, W, h, nullptr);
        gat_attn6<false><<<dim3(32 * NJT), dim3(256), 0, stream>>>(h, adj, a, po, pl);
        gat_reduce<<<dim3(512), dim3(256), 0, stream>>>(po, pl, out);
    } else {
        // fallback: atomic accumulation (1.06 MB workspace)
        float* osum = h + (size_t)Nn * FO;
        float* lsum = osum + (size_t)Nn * FO;
        gat_xw<<<dim3(1024), dim3(256), 0, stream>>>(x, W, h, osum);   // zeros osum+lsum
        gat_attn6<true><<<dim3(32 * NJT), dim3(256), 0, stream>>>(h, adj, a, osum, lsum);
        gat_fin<<<dim3(512), dim3(256), 0, stream>>>(osum, lsum, out);
    }
}

// Round 7
// 121.474 us; speedup vs baseline: 1.3212x; 1.1003x over previous
//
#include <hip/hip_runtime.h>

#define Nn 2048
#define FIN 512
#define FO 64
#define SHIFT 20.0f
#define NJT 32
#define HS 68                 // hi/hj row stride (floats): 272B, 16B-aligned float4 blocks
#define PTS2 132              // pT row stride (floats): [64 j][128 i + pad], 528B 16B-aligned
#define ZTOT (Nn * FO + Nn)   // osum + lsum floats (fallback path only)

// LDS swizzles -- each applied identically on write and read (both-sides rule):
// hi: e-phase reads hit rows i0+d with dRow=8 across li -> XOR f4-block with (r>>3).
#define HXI(r, f) ((r) * HS + ((((f) >> 2) ^ (((r) >> 3) & 15)) << 2))
// hj: e-phase reads hit rows 4*lj+d with dRow=4 across lj -> XOR with (r>>2) (round-4-proven HX).
#define HXJ(r, f) ((r) * HS + ((((f) >> 2) ^ (((r) >> 2) & 15)) << 2))
// pT: [j][i]; XOR i-block with j&7 -- spreads PV writes across banks while keeping each
// wave's cells inside its own 32-i physical slice (no-barrier same-wave write->read safe).
#define PX(j, i)  ((j) * PTS2 + ((((i) >> 2) ^ ((j) & 7)) << 2))

// ---------------- K1: h = x @ W  (proven) + optional zeroing (fallback path) ----------------
__global__ __launch_bounds__(256) void gat_xw(const float* __restrict__ x,
                                              const float* __restrict__ W,
                                              float* __restrict__ h,
                                              float* __restrict__ z) {
    const int gt = blockIdx.x * 256 + threadIdx.x;
    if (z != nullptr && gt < ZTOT) z[gt] = 0.f;

    __shared__ float part[2][2][FO];
    const int wave = threadIdx.x >> 6;
    const int lane = threadIdx.x & 63;
    const int rs = wave >> 1;
    const int kh = wave & 1;
    int row = blockIdx.x * 2 + rs;
    row = __builtin_amdgcn_readfirstlane(row);
    const float* xr = x + (size_t)row * FIN + kh * (FIN / 2);
    const float* Wp = W + (size_t)kh * (FIN / 2) * FO;
    float acc = 0.f;
#pragma unroll 2
    for (int k = 0; k < FIN / 2; k += 8) {
        float4 xa = *(const float4*)(xr + k);
        float4 xb = *(const float4*)(xr + k + 4);
        acc = fmaf(xa.x, Wp[(k + 0) * FO + lane], acc);
        acc = fmaf(xa.y, Wp[(k + 1) * FO + lane], acc);
        acc = fmaf(xa.z, Wp[(k + 2) * FO + lane], acc);
        acc = fmaf(xa.w, Wp[(k + 3) * FO + lane], acc);
        acc = fmaf(xb.x, Wp[(k + 4) * FO + lane], acc);
        acc = fmaf(xb.y, Wp[(k + 5) * FO + lane], acc);
        acc = fmaf(xb.z, Wp[(k + 6) * FO + lane], acc);
        acc = fmaf(xb.w, Wp[(k + 7) * FO + lane], acc);
    }
    part[rs][kh][lane] = acc;
    __syncthreads();
    if (threadIdx.x < 128) {
        const int r2 = threadIdx.x >> 6;
        const int l2 = threadIdx.x & 63;
        h[((size_t)blockIdx.x * 2 + r2) * FO + l2] = part[r2][0][l2] + part[r2][1][l2];
    }
}

// ---------------- K2: 8ix4j register-tiled attn, all hot operands in LDS ----------------
// Block = 256 thr = 4 waves, tile 128i x 64j (grid 16x32 = 512 blocks, 2/CU, LDS 52.5KB).
// Wave w covers i in [ib+32w, ib+32w+32); lane (li=lane&3, lj=lane>>2) owns 8i x 4j.
// e-phase: 12 b128 reads per f4-step feed 32 e-values (0.375 reads/pair; round-4 was 0.5).
// PV: lane -> 8i x 4f; 3 b128 per j feed 32 fmas (round-4: 2 per 16). DS instrs per
// e-value drop ~22% => DS-pipe floor ~21.5 -> ~16.7us. pT unions over hi (dead after
// e-phase), fenced by barrier 2; pT write->read is same-wave logical cells (no barrier,
// round-6-proven pattern).
template <bool ATOMIC>
__global__ __launch_bounds__(256, 4) void gat_attn7(const float* __restrict__ h,
                                                    const int* __restrict__ adj,
                                                    const float* __restrict__ a,
                                                    float* __restrict__ po,
                                                    float* __restrict__ pl) {
    __shared__ __align__(16) float up[128 * HS];    // union: hi_s (HXI) / pT_s (PX)
    __shared__ __align__(16) float hj_s[64 * HS];   // HXJ
    __shared__ float a_s[FO];
    float* hi_s = up;
    float* pT_s = up;

    const int tid = threadIdx.x;
    const int w = tid >> 6;
    const int lane = tid & 63;
    const int li = lane & 3;
    const int lj = lane >> 2;
    const int it = blockIdx.x >> 5;          // 0..15
    const int jt = blockIdx.x & (NJT - 1);   // 0..31
    const int ib = it * 128;
    const int jb = jt * 64;
    const int i0 = 32 * w + 8 * li;          // lane's local i-row base (8 rows)

    // stage hi (128 x 64) and hj (64 x 64), swizzled dests
    for (int g4 = tid; g4 < 2048; g4 += 256) {
        const int row = g4 >> 4;
        const int f0 = (g4 & 15) * 4;
        *(float4*)&hi_s[HXI(row, f0)] = *(const float4*)(h + (size_t)ib * FO + (size_t)g4 * 4);
    }
    for (int g4 = tid; g4 < 1024; g4 += 256) {
        const int row = g4 >> 4;
        const int f0 = (g4 & 15) * 4;
        *(float4*)&hj_s[HXJ(row, f0)] = *(const float4*)(h + (size_t)jb * FO + (size_t)g4 * 4);
    }
    if (tid < FO) a_s[tid] = a[tid];
    __syncthreads();

    // ---- e-phase: e[di][dj] = sum_f a_f * |hi - hj|, 8i x 4j per lane, all b128 ----
    float e[8][4];
#pragma unroll
    for (int di = 0; di < 8; di++)
#pragma unroll
        for (int dj = 0; dj < 4; dj++) e[di][dj] = 0.f;

#pragma unroll 4
    for (int f4 = 0; f4 < 16; f4++) {
        const float4 av = *(const float4*)&a_s[f4 * 4];
        float4 hi4[8], hj4[4];
#pragma unroll
        for (int d = 0; d < 8; d++) hi4[d] = *(const float4*)&hi_s[HXI(i0 + d, f4 * 4)];
#pragma unroll
        for (int d = 0; d < 4; d++) hj4[d] = *(const float4*)&hj_s[HXJ(4 * lj + d, f4 * 4)];
#pragma unroll
        for (int di = 0; di < 8; di++)
#pragma unroll
            for (int dj = 0; dj < 4; dj++) {
                e[di][dj] = fmaf(fabsf(hi4[di].x - hj4[dj].x), av.x, e[di][dj]);
                e[di][dj] = fmaf(fabsf(hi4[di].y - hj4[dj].y), av.y, e[di][dj]);
                e[di][dj] = fmaf(fabsf(hi4[di].z - hj4[dj].z), av.z, e[di][dj]);
                e[di][dj] = fmaf(fabsf(hi4[di].w - hj4[dj].w), av.w, e[di][dj]);
            }
    }

    // ---- p = adj ? exp(relu(e) - SHIFT) : 0 ; row sums ----
    float ls[8];
#pragma unroll
    for (int di = 0; di < 8; di++) ls[di] = 0.f;
#pragma unroll
    for (int di = 0; di < 8; di++) {
        const int4 am = *(const int4*)(adj + (size_t)(ib + i0 + di) * Nn + (jb + 4 * lj));
        const int* ap = (const int*)&am;
#pragma unroll
        for (int dj = 0; dj < 4; dj++) {
            const float p = (ap[dj] > 0) ? __expf(fmaxf(e[di][dj], 0.f) - SHIFT) : 0.f;
            e[di][dj] = p;
            ls[di] += p;
        }
    }

    // all waves must be done reading hi_s before pT overwrites it (union)
    __syncthreads();

    // pT writes: [j][i] layout; lane writes its 8 i's for each of its 4 j's (2 b128 per j)
#pragma unroll
    for (int dj = 0; dj < 4; dj++) {
        const int j = 4 * lj + dj;
        *(float4*)&pT_s[PX(j, i0)] =
            make_float4(e[0][dj], e[1][dj], e[2][dj], e[3][dj]);
        *(float4*)&pT_s[PX(j, i0 + 4)] =
            make_float4(e[4][dj], e[5][dj], e[6][dj], e[7][dj]);
    }
    // no barrier: PV reads only this wave's own logical cells (same-wave DS FIFO)

    // ---- PV: lane -> (8i x 4f): i = ib+i0+di, f = 4*lj+c ----
    float pv[8][4];
#pragma unroll
    for (int di = 0; di < 8; di++)
#pragma unroll
        for (int c = 0; c < 4; c++) pv[di][c] = 0.f;

#pragma unroll 4
    for (int j = 0; j < 64; j++) {
        const float4 pj0 = *(const float4*)&pT_s[PX(j, i0)];      // p for i0..i0+3
        const float4 pj1 = *(const float4*)&pT_s[PX(j, i0 + 4)];  // p for i0+4..i0+7
        const float4 hv = *(const float4*)&hj_s[HXJ(j, 4 * lj)];
        pv[0][0] = fmaf(pj0.x, hv.x, pv[0][0]); pv[0][1] = fmaf(pj0.x, hv.y, pv[0][1]);
        pv[0][2] = fmaf(pj0.x, hv.z, pv[0][2]); pv[0][3] = fmaf(pj0.x, hv.w, pv[0][3]);
        pv[1][0] = fmaf(pj0.y, hv.x, pv[1][0]); pv[1][1] = fmaf(pj0.y, hv.y, pv[1][1]);
        pv[1][2] = fmaf(pj0.y, hv.z, pv[1][2]); pv[1][3] = fmaf(pj0.y, hv.w, pv[1][3]);
        pv[2][0] = fmaf(pj0.z, hv.x, pv[2][0]); pv[2][1] = fmaf(pj0.z, hv.y, pv[2][1]);
        pv[2][2] = fmaf(pj0.z, hv.z, pv[2][2]); pv[2][3] = fmaf(pj0.z, hv.w, pv[2][3]);
        pv[3][0] = fmaf(pj0.w, hv.x, pv[3][0]); pv[3][1] = fmaf(pj0.w, hv.y, pv[3][1]);
        pv[3][2] = fmaf(pj0.w, hv.z, pv[3][2]); pv[3][3] = fmaf(pj0.w, hv.w, pv[3][3]);
        pv[4][0] = fmaf(pj1.x, hv.x, pv[4][0]); pv[4][1] = fmaf(pj1.x, hv.y, pv[4][1]);
        pv[4][2] = fmaf(pj1.x, hv.z, pv[4][2]); pv[4][3] = fmaf(pj1.x, hv.w, pv[4][3]);
        pv[5][0] = fmaf(pj1.y, hv.x, pv[5][0]); pv[5][1] = fmaf(pj1.y, hv.y, pv[5][1]);
        pv[5][2] = fmaf(pj1.y, hv.z, pv[5][2]); pv[5][3] = fmaf(pj1.y, hv.w, pv[5][3]);
        pv[6][0] = fmaf(pj1.z, hv.x, pv[6][0]); pv[6][1] = fmaf(pj1.z, hv.y, pv[6][1]);
        pv[6][2] = fmaf(pj1.z, hv.z, pv[6][2]); pv[6][3] = fmaf(pj1.z, hv.w, pv[6][3]);
        pv[7][0] = fmaf(pj1.w, hv.x, pv[7][0]); pv[7][1] = fmaf(pj1.w, hv.y, pv[7][1]);
        pv[7][2] = fmaf(pj1.w, hv.z, pv[7][2]); pv[7][3] = fmaf(pj1.w, hv.w, pv[7][3]);
    }

    // ---- epilogue: reduce ls over lj lanes; partial stores ----
#pragma unroll
    for (int di = 0; di < 8; di++) {
        float v = ls[di];
        v += __shfl_xor(v, 4, 64);
        v += __shfl_xor(v, 8, 64);
        v += __shfl_xor(v, 16, 64);
        v += __shfl_xor(v, 32, 64);
        ls[di] = v;
    }

    if constexpr (!ATOMIC) {
        if (lj == 0) {
#pragma unroll
            for (int di = 0; di < 8; di++)
                pl[(size_t)jt * Nn + (ib + i0 + di)] = ls[di];
        }
#pragma unroll
        for (int di = 0; di < 8; di++)
            *(float4*)&po[((size_t)jt * Nn + (ib + i0 + di)) * FO + 4 * lj] =
                make_float4(pv[di][0], pv[di][1], pv[di][2], pv[di][3]);
    } else {
        if (lj == 0) {
#pragma unroll
            for (int di = 0; di < 8; di++)
                atomicAdd(&pl[ib + i0 + di], ls[di]);
        }
#pragma unroll
        for (int di = 0; di < 8; di++) {
#pragma unroll
            for (int c = 0; c < 4; c++)
                atomicAdd(&po[(size_t)(ib + i0 + di) * FO + 4 * lj + c], pv[di][c]);
        }
    }
}

// ---------------- K3: out = relu(sum_jt po / sum_jt pl) ----------------
__global__ __launch_bounds__(256) void gat_reduce(const float* __restrict__ po,
                                                  const float* __restrict__ pl,
                                                  float* __restrict__ out) {
    const int t = blockIdx.x * 256 + threadIdx.x;   // grid 512 -> 131072 = Nn*FO
    const int i = t >> 6;
    float s = 0.f;
#pragma unroll
    for (int p = 0; p < NJT; p++) s += po[(size_t)p * (Nn * FO) + t];
    float l = 0.f;
#pragma unroll
    for (int p = 0; p < NJT; p++) l += pl[p * Nn + i];   // wave-uniform addr -> broadcast
    out[t] = fmaxf(s / l, 0.f);
}

// ---------------- fallback K3: out = relu(osum / lsum) ----------------
__global__ __launch_bounds__(256) void gat_fin(const float* __restrict__ osum,
                                               const float* __restrict__ lsum,
                                               float* __restrict__ out) {
    const int t = blockIdx.x * 256 + threadIdx.x;
    out[t] = fmaxf(osum[t] / lsum[t >> 6], 0.f);
}

extern "C" void kernel_launch(void* const* d_in, const int* in_sizes, int n_in,
                              void* d_out, int out_size, void* d_ws, size_t ws_size,
                              hipStream_t stream) {
    const float* x   = (const float*)d_in[0];
    const int*   adj = (const int*)d_in[1];
    const float* W   = (const float*)d_in[2];
    const float* a   = (const float*)d_in[3];
    float* out = (float*)d_out;

    float* h = (float*)d_ws;                                   // Nn*FO floats
    const size_t need = ((size_t)Nn * FO + (size_t)NJT * Nn * FO + (size_t)NJT * Nn) * 4;

    if (ws_size >= need) {
        // no-atomic path: private partials + reduction
        float* po = h + (size_t)Nn * FO;                       // NJT*Nn*FO floats
        float* pl = po + (size_t)NJT * Nn * FO;                // NJT*Nn floats
        gat_xw<<<dim3(1024), dim3(256), 0, stream>>>(x, W, h, nullptr);
        gat_attn7<false><<<dim3(16 * NJT), dim3(256), 0, stream>>>(h, adj, a, po, pl);
        gat_reduce<<<dim3(512), dim3(256), 0, stream>>>(po, pl, out);
    } else {
        // fallback: atomic accumulation (1.06 MB workspace)
        float* osum = h + (size_t)Nn * FO;
        float* lsum = osum + (size_t)Nn * FO;
        gat_xw<<<dim3(1024), dim3(256), 0, stream>>>(x, W, h, osum);   // zeros osum+lsum
        gat_attn7<true><<<dim3(16 * NJT), dim3(256), 0, stream>>>(h, adj, a, osum, lsum);
        gat_fin<<<dim3(512), dim3(256), 0, stream>>>(osum, lsum, out);
    }
}

// Round 9
// 118.670 us; speedup vs baseline: 1.3524x; 1.0236x over previous
//
#include <hip/hip_runtime.h>

#define Nn 2048
#define FIN 512
#define FO 64
#define SHIFT 20.0f
#define NP 32                       // tiles per dimension == partial slices
#define NB ((NP * (NP + 1)) / 2)    // 528 triangular blocks
#define HS 68                       // hi/hj row stride: 272B, 16B-aligned float4 blocks
#define PTS 68                      // pT row stride: 272B, 16B-aligned float4 rows
#define ZTOT (Nn * FO + Nn)         // osum + lsum floats (fallback path only)

// round-4-proven f4-block XOR swizzle (read/write consistent)
#define HX(r, f) ((r) * HS + ((((f) >> 2) ^ (((r) >> 2) & 15)) << 2))

// ---------------- K1: h = x @ W  (proven) + optional zeroing (fallback path) ----------------
__global__ __launch_bounds__(256) void gat_xw(const float* __restrict__ x,
                                              const float* __restrict__ W,
                                              float* __restrict__ h,
                                              float* __restrict__ z) {
    const int gt = blockIdx.x * 256 + threadIdx.x;
    if (z != nullptr && gt < ZTOT) z[gt] = 0.f;

    __shared__ float part[2][2][FO];
    const int wave = threadIdx.x >> 6;
    const int lane = threadIdx.x & 63;
    const int rs = wave >> 1;
    const int kh = wave & 1;
    int row = blockIdx.x * 2 + rs;
    row = __builtin_amdgcn_readfirstlane(row);
    const float* xr = x + (size_t)row * FIN + kh * (FIN / 2);
    const float* Wp = W + (size_t)kh * (FIN / 2) * FO;
    float acc = 0.f;
#pragma unroll 2
    for (int k = 0; k < FIN / 2; k += 8) {
        float4 xa = *(const float4*)(xr + k);
        float4 xb = *(const float4*)(xr + k + 4);
        acc = fmaf(xa.x, Wp[(k + 0) * FO + lane], acc);
        acc = fmaf(xa.y, Wp[(k + 1) * FO + lane], acc);
        acc = fmaf(xa.z, Wp[(k + 2) * FO + lane], acc);
        acc = fmaf(xa.w, Wp[(k + 3) * FO + lane], acc);
        acc = fmaf(xb.x, Wp[(k + 4) * FO + lane], acc);
        acc = fmaf(xb.y, Wp[(k + 5) * FO + lane], acc);
        acc = fmaf(xb.z, Wp[(k + 6) * FO + lane], acc);
        acc = fmaf(xb.w, Wp[(k + 7) * FO + lane], acc);
    }
    part[rs][kh][lane] = acc;
    __syncthreads();
    if (threadIdx.x < 128) {
        const int r2 = threadIdx.x >> 6;
        const int l2 = threadIdx.x & 63;
        h[((size_t)blockIdx.x * 2 + r2) * FO + l2] = part[r2][0][l2] + part[r2][1][l2];
    }
}

// ---------------- K2: symmetric-pair attn -- one e-phase serves two output tiles ----------------
// Triangular grid: block b -> (it <= jt). e[i][j] = sum_f a_f*|hi-hj| and
// E = exp(relu(e)-SHIFT) are SYMMETRIC pre-mask, so an off-diagonal block computes the
// e-phase once and emits BOTH tiles: dir-a (rows ib, mask adj[i][j], PV over hj) and
// dir-b (rows jb, mask adj[j][i], PV over hi). Diagonal blocks do dir-a only.
// All lane maps / swizzles / numerics are round-4-proven fp32. pTa write->read is
// same-wave columns (no barrier, round-6-proven); pTb is cross-wave -> one barrier.
// ls_b needs no shuffle: every lj lane accumulates the full sum inside PV_b (broadcast).
template <bool ATOMIC>
__global__ __launch_bounds__(256, 4) void gat_attn9(const float* __restrict__ h,
                                                    const int* __restrict__ adj,
                                                    const float* __restrict__ a,
                                                    float* __restrict__ po,
                                                    float* __restrict__ pl) {
    __shared__ __align__(16) float hi_s[64 * HS];
    __shared__ __align__(16) float hj_s[64 * HS];
    __shared__ __align__(16) float pTa[64 * PTS];   // [j][i]
    __shared__ __align__(16) float pTb[64 * PTS];   // [i][j]
    __shared__ float a_s[FO];

    // triangular decode: off(t) = t*NP - t*(t-1)/2 ; it = row of b, jt = it + (b - off(it))
    const int b = blockIdx.x;
    int it = (int)((65.0f - sqrtf(4225.0f - 8.0f * (float)b)) * 0.5f);
    while ((it + 1) * NP - (((it + 1) * it) >> 1) <= b) it++;
    while (it * NP - ((it * (it - 1)) >> 1) > b) it--;
    const int jt = it + (b - (it * NP - ((it * (it - 1)) >> 1)));
    const bool diag = (it == jt);

    const int tid = threadIdx.x;
    const int w = tid >> 6;
    const int lane = tid & 63;
    const int li = lane & 3;
    const int lj = lane >> 2;
    const int ib = it * 64;
    const int jb = jt * 64;
    const int iw = w * 16;

    // stage hi and hj tiles (fp32, HX-swizzled) -- round-4-proven
    for (int g4 = tid; g4 < 1024; g4 += 256) {
        const int row = g4 >> 4;
        const int f0 = (g4 & 15) * 4;
        *(float4*)&hi_s[HX(row, f0)] = *(const float4*)(h + (size_t)ib * FO + (size_t)g4 * 4);
        *(float4*)&hj_s[HX(row, f0)] = *(const float4*)(h + (size_t)jb * FO + (size_t)g4 * 4);
    }
    if (tid < FO) a_s[tid] = a[tid];
    __syncthreads();   // B0

    // ---- e-phase (round-4-proven): e[di][dj] = sum_f a_f * |hi - hj| ----
    float e[4][4];
#pragma unroll
    for (int di = 0; di < 4; di++)
#pragma unroll
        for (int dj = 0; dj < 4; dj++) e[di][dj] = 0.f;

#pragma unroll 4
    for (int f4 = 0; f4 < 16; f4++) {
        const float4 av = *(const float4*)&a_s[f4 * 4];
        float4 hi4[4], hj4[4];
#pragma unroll
        for (int d = 0; d < 4; d++) {
            hi4[d] = *(const float4*)&hi_s[HX(iw + 4 * li + d, f4 * 4)];
            hj4[d] = *(const float4*)&hj_s[HX(4 * lj + d, f4 * 4)];
        }
#pragma unroll
        for (int di = 0; di < 4; di++)
#pragma unroll
            for (int dj = 0; dj < 4; dj++) {
                e[di][dj] = fmaf(fabsf(hi4[di].x - hj4[dj].x), av.x, e[di][dj]);
                e[di][dj] = fmaf(fabsf(hi4[di].y - hj4[dj].y), av.y, e[di][dj]);
                e[di][dj] = fmaf(fabsf(hi4[di].z - hj4[dj].z), av.z, e[di][dj]);
                e[di][dj] = fmaf(fabsf(hi4[di].w - hj4[dj].w), av.w, e[di][dj]);
            }
    }

    // ---- E = exp(relu(e) - SHIFT), UNMASKED (symmetric; shared by both directions) ----
#pragma unroll
    for (int di = 0; di < 4; di++)
#pragma unroll
        for (int dj = 0; dj < 4; dj++)
            e[di][dj] = __expf(fmaxf(e[di][dj], 0.f) - SHIFT);

    // ---- direction a: mask adj[i][j]; ls_a; pTa[j][i] ----
    int4 ama[4];
#pragma unroll
    for (int di = 0; di < 4; di++)
        ama[di] = *(const int4*)(adj + (size_t)(ib + iw + 4 * li + di) * Nn + (jb + 4 * lj));
#define PA(di, dj) ((((const int*)&ama[di])[dj] > 0) ? e[di][dj] : 0.f)

    float lsa[4];
#pragma unroll
    for (int di = 0; di < 4; di++) {
        lsa[di] = 0.f;
#pragma unroll
        for (int dj = 0; dj < 4; dj++) lsa[di] += PA(di, dj);
    }
#pragma unroll
    for (int dj = 0; dj < 4; dj++) {
        *(float4*)&pTa[(4 * lj + dj) * PTS + iw + 4 * li] =
            make_float4(PA(0, dj), PA(1, dj), PA(2, dj), PA(3, dj));
    }

    // ---- direction b (off-diagonal only): mask adj[j][i]; pTb[i][j] ----
    if (!diag) {
        int4 amb[4];
#pragma unroll
        for (int dj = 0; dj < 4; dj++)
            amb[dj] = *(const int4*)(adj + (size_t)(jb + 4 * lj + dj) * Nn + (ib + iw + 4 * li));
#define PB(di, dj) ((((const int*)&amb[dj])[di] > 0) ? e[di][dj] : 0.f)
#pragma unroll
        for (int di = 0; di < 4; di++) {
            *(float4*)&pTb[(iw + 4 * li + di) * PTS + 4 * lj] =
                make_float4(PB(di, 0), PB(di, 1), PB(di, 2), PB(di, 3));
        }
    }

    // ---- PV_a (round-4-proven): lane -> (4i x 4f); pTa same-wave cols, no barrier ----
    float pv[4][4];
#pragma unroll
    for (int u = 0; u < 4; u++)
#pragma unroll
        for (int v2 = 0; v2 < 4; v2++) pv[u][v2] = 0.f;

#pragma unroll 4
    for (int j = 0; j < 64; j++) {
        const float4 pj = *(const float4*)&pTa[j * PTS + iw + 4 * li];
        const float4 hv = *(const float4*)&hj_s[HX(j, 4 * lj)];
        pv[0][0] = fmaf(pj.x, hv.x, pv[0][0]); pv[0][1] = fmaf(pj.x, hv.y, pv[0][1]);
        pv[0][2] = fmaf(pj.x, hv.z, pv[0][2]); pv[0][3] = fmaf(pj.x, hv.w, pv[0][3]);
        pv[1][0] = fmaf(pj.y, hv.x, pv[1][0]); pv[1][1] = fmaf(pj.y, hv.y, pv[1][1]);
        pv[1][2] = fmaf(pj.y, hv.z, pv[1][2]); pv[1][3] = fmaf(pj.y, hv.w, pv[1][3]);
        pv[2][0] = fmaf(pj.z, hv.x, pv[2][0]); pv[2][1] = fmaf(pj.z, hv.y, pv[2][1]);
        pv[2][2] = fmaf(pj.z, hv.z, pv[2][2]); pv[2][3] = fmaf(pj.z, hv.w, pv[2][3]);
        pv[3][0] = fmaf(pj.w, hv.x, pv[3][0]); pv[3][1] = fmaf(pj.w, hv.y, pv[3][1]);
        pv[3][2] = fmaf(pj.w, hv.z, pv[3][2]); pv[3][3] = fmaf(pj.w, hv.w, pv[3][3]);
    }

    // ---- epilogue a: reduce ls_a over lj; store partial slice jt, rows ib ----
#pragma unroll
    for (int di = 0; di < 4; di++) {
        float v = lsa[di];
        v += __shfl_xor(v, 4, 64);
        v += __shfl_xor(v, 8, 64);
        v += __shfl_xor(v, 16, 64);
        v += __shfl_xor(v, 32, 64);
        lsa[di] = v;
    }
    if constexpr (!ATOMIC) {
        if (lj == 0) {
#pragma unroll
            for (int di = 0; di < 4; di++)
                pl[(size_t)jt * Nn + (ib + iw + 4 * li + di)] = lsa[di];
        }
#pragma unroll
        for (int di = 0; di < 4; di++)
            *(float4*)&po[((size_t)jt * Nn + (ib + iw + 4 * li + di)) * FO + 4 * lj] =
                make_float4(pv[di][0], pv[di][1], pv[di][2], pv[di][3]);
    } else {
        if (lj == 0) {
#pragma unroll
            for (int di = 0; di < 4; di++)
                atomicAdd(&pl[ib + iw + 4 * li + di], lsa[di]);
        }
#pragma unroll
        for (int di = 0; di < 4; di++) {
#pragma unroll
            for (int v2 = 0; v2 < 4; v2++)
                atomicAdd(&po[(size_t)(ib + iw + 4 * li + di) * FO + 4 * lj + v2], pv[di][v2]);
        }
    }

    // ---- PV_b (off-diagonal): out rows jb+[iw,iw+16), sum over i; pTb cross-wave ----
    if (!diag) {
        __syncthreads();   // B1: all pTb writes visible (block-uniform branch)

        float pvb[4][4];
        float lsb[4];
#pragma unroll
        for (int u = 0; u < 4; u++) {
            lsb[u] = 0.f;
#pragma unroll
            for (int v2 = 0; v2 < 4; v2++) pvb[u][v2] = 0.f;
        }

#pragma unroll 4
        for (int i = 0; i < 64; i++) {
            const float4 pj = *(const float4*)&pTb[i * PTS + iw + 4 * li];   // p_b for j-rows iw+4li+0..3
            const float4 hv = *(const float4*)&hi_s[HX(i, 4 * lj)];
            lsb[0] += pj.x; lsb[1] += pj.y; lsb[2] += pj.z; lsb[3] += pj.w;
            pvb[0][0] = fmaf(pj.x, hv.x, pvb[0][0]); pvb[0][1] = fmaf(pj.x, hv.y, pvb[0][1]);
            pvb[0][2] = fmaf(pj.x, hv.z, pvb[0][2]); pvb[0][3] = fmaf(pj.x, hv.w, pvb[0][3]);
            pvb[1][0] = fmaf(pj.y, hv.x, pvb[1][0]); pvb[1][1] = fmaf(pj.y, hv.y, pvb[1][1]);
            pvb[1][2] = fmaf(pj.y, hv.z, pvb[1][2]); pvb[1][3] = fmaf(pj.y, hv.w, pvb[1][3]);
            pvb[2][0] = fmaf(pj.z, hv.x, pvb[2][0]); pvb[2][1] = fmaf(pj.z, hv.y, pvb[2][1]);
            pvb[2][2] = fmaf(pj.z, hv.z, pvb[2][2]); pvb[2][3] = fmaf(pj.z, hv.w, pvb[2][3]);
            pvb[3][0] = fmaf(pj.w, hv.x, pvb[3][0]); pvb[3][1] = fmaf(pj.w, hv.y, pvb[3][1]);
            pvb[3][2] = fmaf(pj.w, hv.z, pvb[3][2]); pvb[3][3] = fmaf(pj.w, hv.w, pvb[3][3]);
        }

        // lsb is already the FULL sum over i (all 16 lj lanes hold identical values)
        if constexpr (!ATOMIC) {
            if (lj == 0) {
#pragma unroll
                for (int d = 0; d < 4; d++)
                    pl[(size_t)it * Nn + (jb + iw + 4 * li + d)] = lsb[d];
            }
#pragma unroll
            for (int d = 0; d < 4; d++)
                *(float4*)&po[((size_t)it * Nn + (jb + iw + 4 * li + d)) * FO + 4 * lj] =
                    make_float4(pvb[d][0], pvb[d][1], pvb[d][2], pvb[d][3]);
        } else {
            if (lj == 0) {
#pragma unroll
                for (int d = 0; d < 4; d++)
                    atomicAdd(&pl[jb + iw + 4 * li + d], lsb[d]);
            }
#pragma unroll
            for (int d = 0; d < 4; d++) {
#pragma unroll
                for (int v2 = 0; v2 < 4; v2++)
                    atomicAdd(&po[(size_t)(jb + iw + 4 * li + d) * FO + 4 * lj + v2], pvb[d][v2]);
            }
        }
    }
#undef PA
#undef PB
}

// ---------------- K3: out = relu(sum_p po / sum_p pl) ----------------
__global__ __launch_bounds__(256) void gat_reduce(const float* __restrict__ po,
                                                  const float* __restrict__ pl,
                                                  float* __restrict__ out) {
    const int t = blockIdx.x * 256 + threadIdx.x;   // grid 512 -> 131072 = Nn*FO
    const int i = t >> 6;
    float s = 0.f;
#pragma unroll
    for (int p = 0; p < NP; p++) s += po[(size_t)p * (Nn * FO) + t];
    float l = 0.f;
#pragma unroll
    for (int p = 0; p < NP; p++) l += pl[p * Nn + i];   // wave-uniform addr -> broadcast
    out[t] = fmaxf(s / l, 0.f);
}

// ---------------- fallback K3: out = relu(osum / lsum) ----------------
__global__ __launch_bounds__(256) void gat_fin(const float* __restrict__ osum,
                                               const float* __restrict__ lsum,
                                               float* __restrict__ out) {
    const int t = blockIdx.x * 256 + threadIdx.x;
    out[t] = fmaxf(osum[t] / lsum[t >> 6], 0.f);
}

extern "C" void kernel_launch(void* const* d_in, const int* in_sizes, int n_in,
                              void* d_out, int out_size, void* d_ws, size_t ws_size,
                              hipStream_t stream) {
    const float* x   = (const float*)d_in[0];
    const int*   adj = (const int*)d_in[1];
    const float* W   = (const float*)d_in[2];
    const float* a   = (const float*)d_in[3];
    float* out = (float*)d_out;

    float* h = (float*)d_ws;                                   // Nn*FO floats
    const size_t need = ((size_t)Nn * FO + (size_t)NP * Nn * FO + (size_t)NP * Nn) * 4;

    if (ws_size >= need) {
        // no-atomic path: private partials + reduction
        float* po = h + (size_t)Nn * FO;                       // NP*Nn*FO floats
        float* pl = po + (size_t)NP * Nn * FO;                 // NP*Nn floats
        gat_xw<<<dim3(1024), dim3(256), 0, stream>>>(x, W, h, nullptr);
        gat_attn9<false><<<dim3(NB), dim3(256), 0, stream>>>(h, adj, a, po, pl);
        gat_reduce<<<dim3(512), dim3(256), 0, stream>>>(po, pl, out);
    } else {
        // fallback: atomic accumulation (1.06 MB workspace)
        float* osum = h + (size_t)Nn * FO;
        float* lsum = osum + (size_t)Nn * FO;
        gat_xw<<<dim3(1024), dim3(256), 0, stream>>>(x, W, h, osum);   // zeros osum+lsum
        gat_attn9<true><<<dim3(NB), dim3(256), 0, stream>>>(h, adj, a, osum, lsum);
        gat_fin<<<dim3(512), dim3(256), 0, stream>>>(osum, lsum, out);
    }
}